// Round 12
// baseline (115.425 us; speedup 1.0000x reference)
//
#include <hip/hip_runtime.h>

typedef short short4v __attribute__((ext_vector_type(4)));
typedef short short8v __attribute__((ext_vector_type(8)));
typedef float float4v __attribute__((ext_vector_type(4)));
typedef unsigned short u16;

#define NB 2
#define NL 2048
#define NS 2048
#define NH 8
#define NE 64
#define HE (NH*NE)    // 512
#define NLT (NL/64)   // 32 l-tiles per (b,h)
#define NST (NS/64)   // 32 s-tiles

// pack two fp32 -> dword of two bf16 (round-to-nearest, half-up)
static __device__ __forceinline__ unsigned pk2bf(float a, float b) {
  union { float f; unsigned u; } x, y; x.f = a; y.f = b;
  return __builtin_amdgcn_perm(y.u + 0x8000u, x.u + 0x8000u, 0x07060302u);
}

// ---------------------------------------------------------------------------
// Single kernel (prepack folded back in — R2/R3 showed DMA-from-images vs
// in-kernel staging are identical on this stall-bound kernel, so the separate
// prepack dispatch was pure overhead). One 256-thr WG = (b,h, 64-row l-tile),
// full S sweep. Register-prefetch pipeline: global fp32 K/V loads for tile
// st+1 issue before compute(st); commit (pk2bf + swizzled LDS write) happens
// after the barrier at st+1. Single LDS buffer (registers are buffer #2).
// Compute core: row-permuted K=32 QK -> in-register relu^2/exp -> K=32 PV,
// softmax denominator on the matrix pipe via ones-B MFMA (R10, verified).
//   K LDS layout: K[s][e-chunk c] stored at chunk p = c ^ fK(s), fK = s{0,1,3}
//   V LDS layout: V^T[e][s-chunk sc] stored at chunk p = sc ^ (e&7)
// ---------------------------------------------------------------------------
static __device__ __forceinline__ int fK(int s) { return (s & 3) | ((s >> 1) & 4); }

__global__ __launch_bounds__(256, 2)
void assa_fwd(const float* __restrict__ qp, const float* __restrict__ kp,
              const float* __restrict__ vp, const float* __restrict__ a1p,
              const float* __restrict__ a2p, float* __restrict__ op)
{
  __shared__ __align__(16) u16 lds_k[64 * 64];
  __shared__ __align__(16) u16 lds_vt[64 * 64];

  const int tid  = threadIdx.x;
  const int wv   = tid >> 6;
  const int lane = tid & 63;
  const int ln15 = lane & 15;
  const int ln7  = lane & 7;
  const int quad = lane >> 4;

  // XCD swizzle: all 32 l-tiles of one (b,h) on one XCD
  const int bid = blockIdx.x;
  const int bh  = bid & 15;
  const int lt  = bid >> 4;
  const int h   = bh & (NH - 1);
  const int b   = bh >> 3;

  const int lbase = lt * 64 + wv * 16;

  // Q B-fragments, pre-scaled by 1/sqrt(64) (exact exponent shift)
  short8v qf0, qf1;
  {
    const float* qrow = qp + ((size_t)(b * NL + lbase + ln15)) * HE + h * NE + quad * 8;
    float4 q0 = *(const float4*)(qrow);
    float4 q1 = *(const float4*)(qrow + 4);
    float4 q2 = *(const float4*)(qrow + 32);
    float4 q3 = *(const float4*)(qrow + 36);
    unsigned d0[4] = { pk2bf(0.125f*q0.x, 0.125f*q0.y), pk2bf(0.125f*q0.z, 0.125f*q0.w),
                       pk2bf(0.125f*q1.x, 0.125f*q1.y), pk2bf(0.125f*q1.z, 0.125f*q1.w) };
    unsigned d1[4] = { pk2bf(0.125f*q2.x, 0.125f*q2.y), pk2bf(0.125f*q2.z, 0.125f*q2.w),
                       pk2bf(0.125f*q3.x, 0.125f*q3.y), pk2bf(0.125f*q3.z, 0.125f*q3.w) };
    qf0 = *(const short8v*)d0;
    qf1 = *(const short8v*)d1;
  }

  // ones B-fragment (bf16 1.0) for the denominator MFMA
  short8v ones8;
  #pragma unroll
  for (int j = 0; j < 8; ++j) ones8[j] = (short)0x3F80;

  const size_t kvb = (size_t)b * NS * HE + h * NE;
  const float* kb = kp + kvb;
  const float* vb = vp + kvb;

  // staging geometry (per lane, per tile)
  const int rsub = lane >> 3;                       // 0..7
  const int kc0  = ln7 ^ (rsub & 3);                // i=0: c = ln7 ^ fK(srow)
  const int kc1  = ln7 ^ ((rsub & 3) | 4);          // i=1 (bit3 of srow = 1)
  const int ksrow0 = wv * 16 + rsub;                // i=0 row
  const int ksrow1 = ksrow0 + 8;                    // i=1 row
  const float* vpl = vb + (size_t)(wv * 16) * HE + lane;  // e = lane

  float4 kpre[4];
  float  vpre[16];

  // prefetch tile 0
  {
    const float* k0 = kb + (size_t)ksrow0 * HE + kc0 * 8;
    const float* k1 = kb + (size_t)ksrow1 * HE + kc1 * 8;
    kpre[0] = *(const float4*)(k0);
    kpre[1] = *(const float4*)(k0 + 4);
    kpre[2] = *(const float4*)(k1);
    kpre[3] = *(const float4*)(k1 + 4);
    #pragma unroll
    for (int jj = 0; jj < 16; ++jj) vpre[jj] = vpl[(size_t)jj * HE];
  }

  float4v acc_s[4], acc_d[4], acc_l;
  #pragma unroll
  for (int t = 0; t < 4; ++t)
    #pragma unroll
    for (int r = 0; r < 4; ++r) { acc_s[t][r] = 0.0f; acc_d[t][r] = 0.0f; }
  #pragma unroll
  for (int r = 0; r < 4; ++r) acc_l[r] = 0.0f;

  const int rperm = 8 * (ln15 >> 2) + (ln15 & 3);          // + 32U + 4c
  const int fk    = (ln15 & 3) | (((ln15 >> 2) & 1) << 2); // fK of that row

  for (int st = 0; st < NST; ++st) {
    __syncthreads();   // previous iteration's LDS reads complete

    // ---- commit prefetched tile to LDS (pk2bf + swizzled writes) ----
    {
      unsigned kd0[4] = { pk2bf(kpre[0].x, kpre[0].y), pk2bf(kpre[0].z, kpre[0].w),
                          pk2bf(kpre[1].x, kpre[1].y), pk2bf(kpre[1].z, kpre[1].w) };
      unsigned kd1[4] = { pk2bf(kpre[2].x, kpre[2].y), pk2bf(kpre[2].z, kpre[2].w),
                          pk2bf(kpre[3].x, kpre[3].y), pk2bf(kpre[3].z, kpre[3].w) };
      *(int4*)(&lds_k[ksrow0 * 64 + ln7 * 8]) = *(const int4*)kd0;
      *(int4*)(&lds_k[ksrow1 * 64 + ln7 * 8]) = *(const int4*)kd1;
      #pragma unroll
      for (int i = 0; i < 2; ++i) {
        const int cs = (2 * wv + i) ^ ln7;         // stored chunk for sc=2wv+i
        unsigned vd[4] = { pk2bf(vpre[8*i+0], vpre[8*i+1]), pk2bf(vpre[8*i+2], vpre[8*i+3]),
                           pk2bf(vpre[8*i+4], vpre[8*i+5]), pk2bf(vpre[8*i+6], vpre[8*i+7]) };
        *(int4*)(&lds_vt[lane * 64 + cs * 8]) = *(const int4*)vd;
      }
    }
    __syncthreads();

    // ---- issue next tile's global loads; they land during compute ----
    if (st + 1 < NST) {
      const float* k0 = kb + (size_t)((st + 1) * 64 + ksrow0) * HE + kc0 * 8;
      const float* k1 = kb + (size_t)((st + 1) * 64 + ksrow1) * HE + kc1 * 8;
      kpre[0] = *(const float4*)(k0);
      kpre[1] = *(const float4*)(k0 + 4);
      kpre[2] = *(const float4*)(k1);
      kpre[3] = *(const float4*)(k1 + 4);
      const float* vn = vpl + (size_t)(st + 1) * 64 * HE;
      #pragma unroll
      for (int jj = 0; jj < 16; ++jj) vpre[jj] = vn[(size_t)jj * HE];
    }

    // ---- compute: 2 x 32-wide s-blocks ----
    #pragma unroll
    for (int U = 0; U < 2; ++U) {
      float4v sa0, sa1;
      #pragma unroll
      for (int r = 0; r < 4; ++r) { sa0[r] = 0.0f; sa1[r] = 0.0f; }
      const u16* krow0 = &lds_k[(32 * U + rperm) * 64];
      const u16* krow1 = krow0 + 4 * 64;
      short8v kf00 = *(const short8v*)(krow0 + (quad ^ fk) * 8);
      short8v kf01 = *(const short8v*)(krow0 + ((4 + quad) ^ fk) * 8);
      short8v kf10 = *(const short8v*)(krow1 + (quad ^ fk) * 8);
      short8v kf11 = *(const short8v*)(krow1 + ((4 + quad) ^ fk) * 8);
      sa0 = __builtin_amdgcn_mfma_f32_16x16x32_bf16(kf00, qf0, sa0, 0, 0, 0);
      sa0 = __builtin_amdgcn_mfma_f32_16x16x32_bf16(kf01, qf1, sa0, 0, 0, 0);
      sa1 = __builtin_amdgcn_mfma_f32_16x16x32_bf16(kf10, qf0, sa1, 0, 0, 0);
      sa1 = __builtin_amdgcn_mfma_f32_16x16x32_bf16(kf11, qf1, sa1, 0, 0, 0);
      // lane (quad,l=ln15): sa0[r] = score[s=32U+8q+r][l], sa1[r] = +4

      float ps[8], pd[8];
      #pragma unroll
      for (int r = 0; r < 4; ++r) {
        float s0 = sa0[r], s1 = sa1[r];
        float r0 = s0 > 0.0f ? s0 : 0.0f;
        float r1 = s1 > 0.0f ? s1 : 0.0f;
        ps[r] = r0 * r0;  ps[4 + r] = r1 * r1;
        pd[r] = __expf(s0); pd[4 + r] = __expf(s1);
      }
      unsigned da[4] = { pk2bf(ps[0], ps[1]), pk2bf(ps[2], ps[3]),
                         pk2bf(ps[4], ps[5]), pk2bf(ps[6], ps[7]) };
      unsigned db[4] = { pk2bf(pd[0], pd[1]), pk2bf(pd[2], pd[3]),
                         pk2bf(pd[4], pd[5]), pk2bf(pd[6], pd[7]) };
      short8v as8 = *(const short8v*)da;   // A[m=l][k=s-32U] for K=32 PV
      short8v ad8 = *(const short8v*)db;

      // denominator on the matrix pipe
      acc_l = __builtin_amdgcn_mfma_f32_16x16x32_bf16(ad8, ones8, acc_l, 0, 0, 0);

      #pragma unroll
      for (int t = 0; t < 4; ++t) {
        short8v vf = *(const short8v*)(&lds_vt[(t * 16 + ln15) * 64 +
                        (((4 * U + quad) ^ ln7) * 8)]);
        acc_s[t] = __builtin_amdgcn_mfma_f32_16x16x32_bf16(as8, vf, acc_s[t], 0, 0, 0);
        acc_d[t] = __builtin_amdgcn_mfma_f32_16x16x32_bf16(ad8, vf, acc_d[t], 0, 0, 0);
      }
    }
  }

  const float w1 = __expf(a1p[0]), w2 = __expf(a2p[0]);
  const float al1 = w1 / (w1 + w2);
  const float al2 = w2 / (w1 + w2);

  // acc_l[r] is the full denominator for row quad*4+r
  float c_d[4];
  #pragma unroll
  for (int r = 0; r < 4; ++r) c_d[r] = al2 / acc_l[r];

  #pragma unroll
  for (int t = 0; t < 4; ++t) {
    #pragma unroll
    for (int r = 0; r < 4; ++r) {
      float val = al1 * acc_s[t][r] + c_d[r] * acc_d[t][r];
      const int l = lbase + quad * 4 + r;
      const int e = t * 16 + ln15;
      op[((size_t)(b * NL + l)) * HE + h * NE + e] = val;
    }
  }
}

extern "C" void kernel_launch(void* const* d_in, const int* in_sizes, int n_in,
                              void* d_out, int out_size, void* d_ws, size_t ws_size,
                              hipStream_t stream) {
  const float* q  = (const float*)d_in[0];
  const float* k  = (const float*)d_in[1];
  const float* v  = (const float*)d_in[2];
  const float* a1 = (const float*)d_in[3];
  const float* a2 = (const float*)d_in[4];
  float* out = (float*)d_out;
  (void)in_sizes; (void)n_in; (void)out_size; (void)d_ws; (void)ws_size;

  assa_fwd<<<dim3(NB * NH * NLT), dim3(256), 0, stream>>>(q, k, v, a1, a2, out);
}

// Round 13
// 112.285 us; speedup vs baseline: 1.0280x; 1.0280x over previous
//
#include <hip/hip_runtime.h>

typedef short short4v __attribute__((ext_vector_type(4)));
typedef short short8v __attribute__((ext_vector_type(8)));
typedef float float4v __attribute__((ext_vector_type(4)));
typedef unsigned short u16;

#define NB 2
#define NL 2048
#define NS 2048
#define NH 8
#define NE 64
#define HE (NH*NE)    // 512
#define NLT (NL/64)   // 32 l-tiles per (b,h)
#define NST (NS/64)   // 32 s-tile images
#define TILE_U16 4096 // one 64x64 bf16 tile image = 8 KB

// pack two fp32 -> dword of two bf16 (round-to-nearest, half-up)
static __device__ __forceinline__ unsigned pk2bf(float a, float b) {
  union { float f; unsigned u; } x, y; x.f = a; y.f = b;
  return __builtin_amdgcn_perm(y.u + 0x8000u, x.u + 0x8000u, 0x07060302u);
}

#define GLD16(gp, lp) __builtin_amdgcn_global_load_lds( \
    (const __attribute__((address_space(1))) void*)(gp), \
    (__attribute__((address_space(3))) void*)(lp), 16, 0, 0)

// K-image swizzle hash: uses s bits {0,1,3} so the permuted QK row set
// (s = 8*(ln15>>2) + (ln15&3) + 4c) still spans all 8 chunk slots.
static __device__ __forceinline__ int fK(int s) { return (s & 3) | ((s >> 1) & 4); }

// ---------------------------------------------------------------------------
// Pre-pass (R10-verified): K,V fp32 -> bf16 tile images in d_ws, in the EXACT
// swizzled byte order the main kernel's LDS wants (K row-major, V transposed).
// K and V in separate blocks (1024 WGs) for latency overlap.
// ---------------------------------------------------------------------------
__global__ __launch_bounds__(256)
void prepack(const float* __restrict__ kp, const float* __restrict__ vp,
             u16* __restrict__ kimg, u16* __restrict__ vimg)
{
  __shared__ __align__(16) u16 ldsv[TILE_U16];

  const int bid  = blockIdx.x;          // 0..1023
  const int tile = bid >> 1;            // bh*NST + st
  const int doV  = bid & 1;
  const int st = tile & (NST - 1);
  const int bh = tile >> 5;
  const int h  = bh & (NH - 1);
  const int b  = bh >> 3;
  const int s0 = st * 64;
  const size_t base = (size_t)b * NS * HE + h * NE;
  const int tid  = threadIdx.x;
  const int wv   = tid >> 6;
  const int lane = tid & 63;
  const int ln7  = lane & 7;

  if (!doV) {
    u16* kt = kimg + (size_t)tile * TILE_U16;
    for (int slot = tid; slot < 512; slot += 256) {
      const int srow = slot >> 3, p = slot & 7, c = p ^ fK(srow);
      const float* src = kp + base + (size_t)(s0 + srow) * HE + c * 8;
      float4 x0 = *(const float4*)src;
      float4 x1 = *(const float4*)(src + 4);
      unsigned d[4] = { pk2bf(x0.x, x0.y), pk2bf(x0.z, x0.w),
                        pk2bf(x1.x, x1.y), pk2bf(x1.z, x1.w) };
      *(int4*)(kt + slot * 8) = *(const int4*)d;
    }
    return;
  }

  u16* vt = vimg + (size_t)tile * TILE_U16;
  {
    const float* vcol = vp + base + (size_t)(s0 + wv * 16) * HE + lane;
    unsigned vr[8];
    #pragma unroll
    for (int jj = 0; jj < 8; ++jj)
      vr[jj] = pk2bf(vcol[(size_t)(2 * jj) * HE], vcol[(size_t)(2 * jj + 1) * HE]);
    #pragma unroll
    for (int i = 0; i < 2; ++i) {
      const int cs = (2 * wv + i) ^ ln7;
      int4 t4 = make_int4((int)vr[4*i+0], (int)vr[4*i+1],
                          (int)vr[4*i+2], (int)vr[4*i+3]);
      *(int4*)(&ldsv[lane * 64 + cs * 8]) = t4;
    }
  }
  __syncthreads();
  {
    const int4* s = (const int4*)ldsv;
    int4* dst = (int4*)vt;
    dst[tid]       = s[tid];
    dst[tid + 256] = s[tid + 256];
  }
}

// ---------------------------------------------------------------------------
// Main (R10 base + BK=128): one 256-thr WG = (b,h, 64-row l-tile), full S.
// Each barrier phase covers TWO 64-row s-images (128 s-rows): halves barrier
// count 32->16 and doubles independent dep chains per phase. Double-buffered
// LDS 2 x [K0 K1 V0 V1] = 64 KB (still 2 blocks/CU). DMA(phase+1) in flight
// during compute(phase). Row-permuted K=32 QK -> in-register relu^2/exp ->
// K=32 PV; softmax denominator on the matrix pipe via ones-B MFMA.
// ---------------------------------------------------------------------------
__global__ __launch_bounds__(256, 2)
void assa_fwd(const float* __restrict__ qp, const u16* __restrict__ kimg,
              const u16* __restrict__ vimg, const float* __restrict__ a1p,
              const float* __restrict__ a2p, float* __restrict__ op)
{
  __shared__ __align__(16) u16 ldsb[2][4 * TILE_U16];  // [buf][K0 K1 V0 V1]

  const int tid  = threadIdx.x;
  const int wv   = tid >> 6;
  const int lane = tid & 63;
  const int ln15 = lane & 15;
  const int ln7  = lane & 7;
  const int quad = lane >> 4;

  // XCD swizzle: all 32 l-tiles of one (b,h) on one XCD
  const int bid = blockIdx.x;
  const int bh  = bid & 15;
  const int lt  = bid >> 4;
  const int h   = bh & (NH - 1);
  const int b   = bh >> 3;

  const int lbase = lt * 64 + wv * 16;

  // Q B-fragments, pre-scaled by 1/sqrt(64) (exact exponent shift)
  short8v qf0, qf1;
  {
    const float* qrow = qp + ((size_t)(b * NL + lbase + ln15)) * HE + h * NE + quad * 8;
    float4 q0 = *(const float4*)(qrow);
    float4 q1 = *(const float4*)(qrow + 4);
    float4 q2 = *(const float4*)(qrow + 32);
    float4 q3 = *(const float4*)(qrow + 36);
    unsigned d0[4] = { pk2bf(0.125f*q0.x, 0.125f*q0.y), pk2bf(0.125f*q0.z, 0.125f*q0.w),
                       pk2bf(0.125f*q1.x, 0.125f*q1.y), pk2bf(0.125f*q1.z, 0.125f*q1.w) };
    unsigned d1[4] = { pk2bf(0.125f*q2.x, 0.125f*q2.y), pk2bf(0.125f*q2.z, 0.125f*q2.w),
                       pk2bf(0.125f*q3.x, 0.125f*q3.y), pk2bf(0.125f*q3.z, 0.125f*q3.w) };
    qf0 = *(const short8v*)d0;
    qf1 = *(const short8v*)d1;
  }

  // ones B-fragment (bf16 1.0) for the denominator MFMA
  short8v ones8;
  #pragma unroll
  for (int j = 0; j < 8; ++j) ones8[j] = (short)0x3F80;

  const size_t tbase = (size_t)bh * NST;

  float4v acc_s[4], acc_d[4], acc_l;
  #pragma unroll
  for (int t = 0; t < 4; ++t)
    #pragma unroll
    for (int r = 0; r < 4; ++r) { acc_s[t][r] = 0.0f; acc_d[t][r] = 0.0f; }
  #pragma unroll
  for (int r = 0; r < 4; ++r) acc_l[r] = 0.0f;

  // DMA one 128-row phase (two images) into buffer nb:
  // waves 0,1 -> K images, waves 2,3 -> V images; 8 GLD16 per wave.
  auto dma_phase = [&](int ph, int nb) {
    const int hf = wv & 1;
    #pragma unroll
    for (int i = 0; i < 2; ++i) {
      const size_t img = tbase + 2 * ph + i;
      const u16* g;
      u16* l;
      if (wv < 2) {
        g = kimg + img * TILE_U16 + hf * 2048 + lane * 8;
        l = &ldsb[nb][i * TILE_U16 + hf * 2048];
      } else {
        g = vimg + img * TILE_U16 + hf * 2048 + lane * 8;
        l = &ldsb[nb][(2 + i) * TILE_U16 + hf * 2048];
      }
      GLD16(g,        l);
      GLD16(g +  512, l +  512);
      GLD16(g + 1024, l + 1024);
      GLD16(g + 1536, l + 1536);
    }
  };

  dma_phase(0, 0);

  const int rperm = 8 * (ln15 >> 2) + (ln15 & 3);          // + 32U + 4c
  const int fk    = (ln15 & 3) | (((ln15 >> 2) & 1) << 2); // fK of that row

  for (int ph = 0; ph < NST / 2; ++ph) {
    __builtin_amdgcn_s_waitcnt(0);
    __syncthreads();
    if (ph + 1 < NST / 2) dma_phase(ph + 1, (ph + 1) & 1);

    #pragma unroll
    for (int sub = 0; sub < 2; ++sub) {
      const u16* kb_l = &ldsb[ph & 1][sub * TILE_U16];
      const u16* vb_l = &ldsb[ph & 1][(2 + sub) * TILE_U16];

      #pragma unroll
      for (int U = 0; U < 2; ++U) {
        float4v sa0, sa1;
        #pragma unroll
        for (int r = 0; r < 4; ++r) { sa0[r] = 0.0f; sa1[r] = 0.0f; }
        const u16* krow0 = &kb_l[(32 * U + rperm) * 64];
        const u16* krow1 = krow0 + 4 * 64;
        short8v kf00 = *(const short8v*)(krow0 + (quad ^ fk) * 8);
        short8v kf01 = *(const short8v*)(krow0 + ((4 + quad) ^ fk) * 8);
        short8v kf10 = *(const short8v*)(krow1 + (quad ^ fk) * 8);
        short8v kf11 = *(const short8v*)(krow1 + ((4 + quad) ^ fk) * 8);
        sa0 = __builtin_amdgcn_mfma_f32_16x16x32_bf16(kf00, qf0, sa0, 0, 0, 0);
        sa0 = __builtin_amdgcn_mfma_f32_16x16x32_bf16(kf01, qf1, sa0, 0, 0, 0);
        sa1 = __builtin_amdgcn_mfma_f32_16x16x32_bf16(kf10, qf0, sa1, 0, 0, 0);
        sa1 = __builtin_amdgcn_mfma_f32_16x16x32_bf16(kf11, qf1, sa1, 0, 0, 0);
        // lane (quad,l=ln15): sa0[r] = score[s=32U+8q+r][l], sa1[r] = +4

        float ps[8], pd[8];
        #pragma unroll
        for (int r = 0; r < 4; ++r) {
          float s0 = sa0[r], s1 = sa1[r];
          float r0 = s0 > 0.0f ? s0 : 0.0f;
          float r1 = s1 > 0.0f ? s1 : 0.0f;
          ps[r] = r0 * r0;  ps[4 + r] = r1 * r1;
          pd[r] = __expf(s0); pd[4 + r] = __expf(s1);
        }
        unsigned da[4] = { pk2bf(ps[0], ps[1]), pk2bf(ps[2], ps[3]),
                           pk2bf(ps[4], ps[5]), pk2bf(ps[6], ps[7]) };
        unsigned db[4] = { pk2bf(pd[0], pd[1]), pk2bf(pd[2], pd[3]),
                           pk2bf(pd[4], pd[5]), pk2bf(pd[6], pd[7]) };
        short8v as8 = *(const short8v*)da;   // A[m=l][k=s-32U] for K=32 PV
        short8v ad8 = *(const short8v*)db;

        // denominator on the matrix pipe
        acc_l = __builtin_amdgcn_mfma_f32_16x16x32_bf16(ad8, ones8, acc_l, 0, 0, 0);

        #pragma unroll
        for (int t = 0; t < 4; ++t) {
          short8v vf = *(const short8v*)(&vb_l[(t * 16 + ln15) * 64 +
                          (((4 * U + quad) ^ ln7) * 8)]);
          acc_s[t] = __builtin_amdgcn_mfma_f32_16x16x32_bf16(as8, vf, acc_s[t], 0, 0, 0);
          acc_d[t] = __builtin_amdgcn_mfma_f32_16x16x32_bf16(ad8, vf, acc_d[t], 0, 0, 0);
        }
      }
    }
  }

  const float w1 = __expf(a1p[0]), w2 = __expf(a2p[0]);
  const float al1 = w1 / (w1 + w2);
  const float al2 = w2 / (w1 + w2);

  // acc_l[r] is the full denominator for row quad*4+r
  float c_d[4];
  #pragma unroll
  for (int r = 0; r < 4; ++r) c_d[r] = al2 / acc_l[r];

  #pragma unroll
  for (int t = 0; t < 4; ++t) {
    #pragma unroll
    for (int r = 0; r < 4; ++r) {
      float val = al1 * acc_s[t][r] + c_d[r] * acc_d[t][r];
      const int l = lbase + quad * 4 + r;
      const int e = t * 16 + ln15;
      op[((size_t)(b * NL + l)) * HE + h * NE + e] = val;
    }
  }
}

extern "C" void kernel_launch(void* const* d_in, const int* in_sizes, int n_in,
                              void* d_out, int out_size, void* d_ws, size_t ws_size,
                              hipStream_t stream) {
  const float* q  = (const float*)d_in[0];
  const float* k  = (const float*)d_in[1];
  const float* v  = (const float*)d_in[2];
  const float* a1 = (const float*)d_in[3];
  const float* a2 = (const float*)d_in[4];
  float* out = (float*)d_out;
  (void)in_sizes; (void)n_in; (void)out_size; (void)ws_size;

  u16* kimg = (u16*)d_ws;                                   // 4 MiB
  u16* vimg = kimg + (size_t)NB * NH * NST * TILE_U16;      // 4 MiB

  prepack<<<dim3(NB * NH * NST * 2), dim3(256), 0, stream>>>(k, v, kimg, vimg);
  assa_fwd<<<dim3(NB * NH * NLT), dim3(256), 0, stream>>>(q, kimg, vimg, a1, a2, out);
}